// Round 18
// baseline (841.784 us; speedup 1.0000x reference)
//
#include <hip/hip_runtime.h>

#define B_   64
#define N_   512
#define R_   256
#define L_   6
#define HID_ 1536

#define BM 128
#define BN 128
#define BK 32
#define LDA_PAD 40   // padded stride for reg-staged A buffers (no bank conflict)
#define LDL 32       // linear stride for global_load_lds buffers

typedef __attribute__((ext_vector_type(4))) float f32x4;
typedef __attribute__((ext_vector_type(8))) __bf16 bf16x8;
typedef __attribute__((ext_vector_type(8))) unsigned short u16x8;
typedef unsigned short u16;
typedef unsigned char  u8;
typedef unsigned int   u32;

__device__ __forceinline__ float silu_f(float x) { return x / (1.0f + __expf(-x)); }

__device__ __forceinline__ float bf2f(u16 h) {
    u32 u = ((u32)h) << 16;
    return __builtin_bit_cast(float, u);
}
// truncation split: x ~= hi + lo with ~17 effective mantissa bits
__device__ __forceinline__ void split2(float x, u16& h, u16& l) {
    u32 u = __builtin_bit_cast(u32, x);
    h = (u16)(u >> 16);
    float r = x - __builtin_bit_cast(float, u & 0xffff0000u);   // exact
    l = (u16)(__builtin_bit_cast(u32, r) >> 16);
}
__device__ __forceinline__ float join2(u16 h, u16 l) {
    return bf2f(h) + bf2f(l);
}
// fp16 storage helpers (probabilities in [0,1])
__device__ __forceinline__ u16 f2h16(float x) {
    _Float16 h = (_Float16)x;
    return __builtin_bit_cast(u16, h);
}
__device__ __forceinline__ float h162f(u16 b) {
    return (float)__builtin_bit_cast(_Float16, b);
}

// ---------------------------------------------------------------------------
// global -> LDS direct (16B/lane). LDS dest is wave-uniform base + lane*16B.
// ---------------------------------------------------------------------------
__device__ __forceinline__ void gll16(const u16* g, u16* l) {
    __builtin_amdgcn_global_load_lds((const __attribute__((address_space(1))) void*)g,
                                     (__attribute__((address_space(3))) void*)l, 16, 0, 0);
}
// 128 rows x 32 cols u16 tile, linear LDS [row*32+col]
__device__ __forceinline__ void stage128(const u16* g, size_t gstride, u16* lds, int t) {
    const int wb = (t >> 6) * 512;
    const int row = t >> 2, col = (t & 3) * 8;
    gll16(g + (size_t)row * gstride + col, lds + wb);
    gll16(g + (size_t)(row + 64) * gstride + col, lds + 2048 + wb);
}
// 64 rows x 32 cols
__device__ __forceinline__ void stage64(const u16* g, size_t gstride, u16* lds, int t) {
    const int wb = (t >> 6) * 512;
    gll16(g + (size_t)(t >> 2) * gstride + (t & 3) * 8, lds + wb);
}

// triple-MFMA on one (ah,al,bh,bl) fragment set
#define TRIPLE1(ACC, AH, AL, BH, BL)                                            \
    ACC = __builtin_amdgcn_mfma_f32_16x16x32_bf16(AH, BH, ACC, 0, 0, 0);        \
    ACC = __builtin_amdgcn_mfma_f32_16x16x32_bf16(AL, BH, ACC, 0, 0, 0);        \
    ACC = __builtin_amdgcn_mfma_f32_16x16x32_bf16(AH, BL, ACC, 0, 0, 0);

// BM=128 x BN=128 core with per-side LDS strides
#define MFMA_TRIPLE_G(ACC, Ash, Asl, Bsh, Bsl, LDA, LDB)                        \
    {                                                                           \
        const int k8 = (lane >> 4) * 8, cl = lane & 15;                         \
        bf16x8 bh[4], bl[4];                                                    \
        _Pragma("unroll")                                                       \
        for (int n = 0; n < 4; ++n) {                                           \
            bh[n] = *(const bf16x8*)&Bsh[(wc * 64 + n * 16 + cl) * LDB + k8];   \
            bl[n] = *(const bf16x8*)&Bsl[(wc * 64 + n * 16 + cl) * LDB + k8];   \
        }                                                                       \
        _Pragma("unroll")                                                       \
        for (int m = 0; m < 4; ++m) {                                           \
            bf16x8 ah = *(const bf16x8*)&Ash[(wr * 64 + m * 16 + cl) * LDA + k8]; \
            bf16x8 al = *(const bf16x8*)&Asl[(wr * 64 + m * 16 + cl) * LDA + k8]; \
            _Pragma("unroll")                                                   \
            for (int n = 0; n < 4; ++n) {                                       \
                TRIPLE1(ACC[m][n], ah, al, bh[n], bl[n])                        \
            }                                                                   \
        }                                                                       \
    }

// ===========================================================================
// C = act(A @ W + bias), A fp32 (on-the-fly split, reg-staged, padded LDS);
// B = WT[Nn,K] hi/lo via global_load_lds (linear LDS).
// ===========================================================================
template<int ACT>
__global__ __launch_bounds__(256)
void k_mf_gemm(const float* __restrict__ Af,
               const u16* __restrict__ WTh, const u16* __restrict__ WTl,
               const float* __restrict__ bias,
               u16* __restrict__ Ch, u16* __restrict__ Cl,
               int M, int Nn, int K)
{
    __shared__ u16 Ash[BM * LDA_PAD], Asl[BM * LDA_PAD];
    __shared__ u16 Bsh[BN * LDL], Bsl[BN * LDL];
    const int t = threadIdx.x, lane = t & 63, w = t >> 6;
    const int wr = w >> 1, wc = w & 1;
    const int m0 = blockIdx.y * BM, n0 = blockIdx.x * BN;
    const int sr = t >> 1, sc = (t & 1) * 16;
    f32x4 acc[4][4] = {};
    for (int k0 = 0; k0 < K; k0 += BK) {
        {
            const float* ga = Af + (size_t)(m0 + sr) * K + k0 + sc;
            u16x8 vh0, vl0, vh1, vl1;
            #pragma unroll
            for (int p = 0; p < 2; ++p) {
                const float4 a = *(const float4*)(ga + p * 8);
                const float4 b = *(const float4*)(ga + p * 8 + 4);
                u16 h, l;
                split2(a.x, h, l); (p ? vh1 : vh0)[0] = h; (p ? vl1 : vl0)[0] = l;
                split2(a.y, h, l); (p ? vh1 : vh0)[1] = h; (p ? vl1 : vl0)[1] = l;
                split2(a.z, h, l); (p ? vh1 : vh0)[2] = h; (p ? vl1 : vl0)[2] = l;
                split2(a.w, h, l); (p ? vh1 : vh0)[3] = h; (p ? vl1 : vl0)[3] = l;
                split2(b.x, h, l); (p ? vh1 : vh0)[4] = h; (p ? vl1 : vl0)[4] = l;
                split2(b.y, h, l); (p ? vh1 : vh0)[5] = h; (p ? vl1 : vl0)[5] = l;
                split2(b.z, h, l); (p ? vh1 : vh0)[6] = h; (p ? vl1 : vl0)[6] = l;
                split2(b.w, h, l); (p ? vh1 : vh0)[7] = h; (p ? vl1 : vl0)[7] = l;
            }
            *(u16x8*)&Ash[sr * LDA_PAD + sc]     = vh0;
            *(u16x8*)&Ash[sr * LDA_PAD + sc + 8] = vh1;
            *(u16x8*)&Asl[sr * LDA_PAD + sc]     = vl0;
            *(u16x8*)&Asl[sr * LDA_PAD + sc + 8] = vl1;
        }
        stage128(WTh + (size_t)n0 * K + k0, K, Bsh, t);
        stage128(WTl + (size_t)n0 * K + k0, K, Bsl, t);
        __syncthreads();
        MFMA_TRIPLE_G(acc, Ash, Asl, Bsh, Bsl, LDA_PAD, LDL)
        __syncthreads();
    }
    const int cl2 = lane & 15, rh = lane >> 4;
    #pragma unroll
    for (int m = 0; m < 4; ++m)
        #pragma unroll
        for (int n = 0; n < 4; ++n) {
            const int col = n0 + wc * 64 + n * 16 + cl2;
            const float bb = bias[col];
            #pragma unroll
            for (int q = 0; q < 4; ++q) {
                const int row = m0 + wr * 64 + m * 16 + rh * 4 + q;
                float v = acc[m][n][q] + bb;
                if (ACT) v = silu_f(v);
                const size_t idx = (size_t)row * Nn + col;
                split2(v, Ch[idx], Cl[idx]);
            }
        }
}

// ===========================================================================
// pw kernel, grid 1024, XCD-swizzled. Single-pass dual-acc at BM2=64.
// DO_T: also emit XT (X transposed) directly from the staged A tiles —
// block n0=0 writes hi plane, n0=1 writes lo plane (balanced, no extra read).
// ===========================================================================
#define BM2 64
template<int DO_P, int DO_T>
__global__ __launch_bounds__(256)
void k_pwt(const u16* __restrict__ Xh, const u16* __restrict__ Xl,
           const u16* __restrict__ WwTh, const u16* __restrict__ WwTl,
           const u16* __restrict__ WgTh, const u16* __restrict__ WgTl,
           const float* __restrict__ bw, const float* __restrict__ bg,
           u16* __restrict__ Ph, u16* __restrict__ Pl,
           u16* __restrict__ XTh, u16* __restrict__ XTl,
           float* __restrict__ f, int step)
{
    __shared__ u16 smem[20480];          // 40 KB
    const int d = blockIdx.x;
    const int t = threadIdx.x;
    const int gid = ((d & 7) << 7) | (d >> 3);             // bijective on [0,1024)
    const int lane = t & 63, w = t >> 6;
    const int m0 = (gid >> 1) * BM2, n0 = (gid & 1) * BN;
    u16* Ash = smem;                     // 64*32
    u16* Asl = smem + 2048;
    u16* Bwh = smem + 4096;              // 128*32 each
    u16* Bwl = smem + 8192;
    u16* Bgh = smem + 12288;
    u16* Bgl = smem + 16384;
    // transposed-write assignment: this block handles one plane
    const u16* Tsrc = (gid & 1) ? Asl : Ash;
    u16*       Tdst = (gid & 1) ? XTl : XTh;
    const int  tb   = m0 >> 9;                 // batch
    const int  ib   = (m0 & 511) + (t & 7) * 8;
    const int  kk   = t >> 3;                  // 0..31
    f32x4 accp[4][2] = {};
    f32x4 accg[4][2] = {};
    for (int k0 = 0; k0 < R_; k0 += BK) {
        stage64(Xh + (size_t)m0 * R_ + k0, R_, Ash, t);
        stage64(Xl + (size_t)m0 * R_ + k0, R_, Asl, t);
        if (DO_P) {
            stage128(WwTh + (size_t)n0 * R_ + k0, R_, Bwh, t);
            stage128(WwTl + (size_t)n0 * R_ + k0, R_, Bwl, t);
        }
        stage128(WgTh + (size_t)n0 * R_ + k0, R_, Bgh, t);
        stage128(WgTl + (size_t)n0 * R_ + k0, R_, Bgl, t);
        __syncthreads();
        {
            const int k8 = (lane >> 4) * 8, cl = lane & 15;
            bf16x8 ah[4], al[4];
            #pragma unroll
            for (int m = 0; m < 4; ++m) {
                ah[m] = *(const bf16x8*)&Ash[(m * 16 + cl) * LDL + k8];
                al[m] = *(const bf16x8*)&Asl[(m * 16 + cl) * LDL + k8];
            }
            #pragma unroll
            for (int n = 0; n < 2; ++n) {
                const int bcol = (w * 32 + n * 16 + cl) * LDL + k8;
                if (DO_P) {
                    bf16x8 bh = *(const bf16x8*)&Bwh[bcol];
                    bf16x8 bl = *(const bf16x8*)&Bwl[bcol];
                    #pragma unroll
                    for (int m = 0; m < 4; ++m) { TRIPLE1(accp[m][n], ah[m], al[m], bh, bl) }
                }
                bf16x8 bh2 = *(const bf16x8*)&Bgh[bcol];
                bf16x8 bl2 = *(const bf16x8*)&Bgl[bcol];
                #pragma unroll
                for (int m = 0; m < 4; ++m) { TRIPLE1(accg[m][n], ah[m], al[m], bh2, bl2) }
            }
        }
        if (DO_T) {
            // write transposed strip XT[tb, k0+kk, ib..ib+8) from staged tile
            u16x8 v;
            #pragma unroll
            for (int e = 0; e < 8; ++e)
                v[e] = Tsrc[((t & 7) * 8 + e) * LDL + kk];
            *(u16x8*)(Tdst + (size_t)tb * R_ * N_ + (size_t)(k0 + kk) * N_ + ib) = v;
        }
        __syncthreads();
    }
    const int cl2 = lane & 15, rh = lane >> 4;
    if (DO_P) {
        #pragma unroll
        for (int m = 0; m < 4; ++m)
            #pragma unroll
            for (int n = 0; n < 2; ++n) {
                const int col = n0 + w * 32 + n * 16 + cl2;
                const float bwv = bw[col];
                #pragma unroll
                for (int q = 0; q < 4; ++q) {
                    const int row = m0 + m * 16 + rh * 4 + q;
                    const size_t idx = (size_t)row * R_ + col;
                    split2(accp[m][n][q] + bwv, Ph[idx], Pl[idx]);
                }
            }
    }
    const int bb = gid >> 4;                     // batch: m0/512
    #pragma unroll
    for (int n = 0; n < 2; ++n) {
        const int col = n0 + w * 32 + n * 16 + cl2;
        const float bias = bg[col];
        float s = 0.0f;
        #pragma unroll
        for (int m = 0; m < 4; ++m)
            #pragma unroll
            for (int q = 0; q < 4; ++q)
                s += silu_f(accg[m][n][q] + bias);
        s += __shfl_xor(s, 16);
        s += __shfl_xor(s, 32);
        if (rh == 0)
            atomicAdd(&f[(size_t)bb * HID_ + step * R_ + col], s);
    }
}

// ===========================================================================
// S-tile = P @ Fn^T masked (bit-packed mask); writes E = fp16(exp(S-M_tile))
// plus per-tile column stats pm, ps.
// ===========================================================================
__global__ __launch_bounds__(256)
void k_mf_abt(const u16* __restrict__ Ph, const u16* __restrict__ Pl,
              const u16* __restrict__ Fh, const u16* __restrict__ Fl,
              const u8* __restrict__ msk, u16* __restrict__ E,
              float* __restrict__ pm, float* __restrict__ ps)
{
    __shared__ u16 Ash[BM * LDL], Asl[BM * LDL];
    __shared__ u16 Bsh[BN * LDL], Bsl[BN * LDL];
    const int t = threadIdx.x, lane = t & 63, w = t >> 6;
    const int wr = w >> 1, wc = w & 1;
    const int b = blockIdx.x;
    const int j0 = blockIdx.y * BN, i0 = blockIdx.z * BM;
    const size_t boff = (size_t)b * N_ * R_;
    f32x4 acc[4][4] = {};
    for (int k0 = 0; k0 < R_; k0 += BK) {
        stage128(Ph + boff + (size_t)i0 * R_ + k0, R_, Ash, t);
        stage128(Pl + boff + (size_t)i0 * R_ + k0, R_, Asl, t);
        stage128(Fh + boff + (size_t)j0 * R_ + k0, R_, Bsh, t);
        stage128(Fl + boff + (size_t)j0 * R_ + k0, R_, Bsl, t);
        __syncthreads();
        MFMA_TRIPLE_G(acc, Ash, Asl, Bsh, Bsl, LDL, LDL)
        __syncthreads();
    }
    const int cl2 = lane & 15, rh = lane >> 4;
    const u8*   mb = msk + ((size_t)b * N_ * N_ >> 3);   // bit-packed per batch
    u16*        Eb = E   + (size_t)b * N_ * N_;
    float* smax = (float*)Ash;         // [8][128]
    float* ssum = (float*)Asl;         // [8][128]
    float* Mcol = (float*)Bsh;         // [128]
    const int slot = wr * 4 + rh;
    u32 mbits[4];
    // pass A: mask bits + thread-local column max (masked -> -1e8)
    #pragma unroll
    for (int n = 0; n < 4; ++n) {
        const int col = wc * 64 + n * 16 + cl2;
        const int bit = cl2 & 7;                  // (j0+col)&7 == cl2&7
        const int bcol = (j0 + col) >> 3;
        u32 mbit = 0;
        float lm = -3.0e38f;
        #pragma unroll
        for (int m = 0; m < 4; ++m)
            #pragma unroll
            for (int q = 0; q < 4; ++q) {
                const int row = i0 + wr * 64 + m * 16 + rh * 4 + q;
                const u32 on = (mb[(row << 6) + bcol] >> bit) & 1u;
                mbit |= on << (m * 4 + q);
                const float v = on ? acc[m][n][q] : -1.0e8f;
                lm = fmaxf(lm, v);
            }
        mbits[n] = mbit;
        smax[slot * 128 + col] = lm;
    }
    __syncthreads();
    if (t < 128) {
        float M = smax[t];
        #pragma unroll
        for (int s2 = 1; s2 < 8; ++s2) M = fmaxf(M, smax[s2 * 128 + t]);
        Mcol[t] = M;
        pm[((size_t)(b * 4 + blockIdx.z) * 512) + j0 + t] = M;
    }
    __syncthreads();
    // pass B: E = fp16(exp(v - M_tile)), accumulate tile column sums
    #pragma unroll
    for (int n = 0; n < 4; ++n) {
        const int col = wc * 64 + n * 16 + cl2;
        const float M = Mcol[col];
        float ls = 0.0f;
        #pragma unroll
        for (int m = 0; m < 4; ++m)
            #pragma unroll
            for (int q = 0; q < 4; ++q) {
                const int row = i0 + wr * 64 + m * 16 + rh * 4 + q;
                const u32 on = (mbits[n] >> (m * 4 + q)) & 1u;
                const float ev = on ? __expf(acc[m][n][q] - M) : 0.0f;
                ls += ev;
                Eb[(size_t)row * N_ + (j0 + col)] = f2h16(ev);
            }
        ssum[slot * 128 + col] = ls;
    }
    __syncthreads();
    if (t < 128) {
        float D = 0.0f;
        #pragma unroll
        for (int s2 = 0; s2 < 8; ++s2) D += ssum[s2 * 128 + t];
        ps[((size_t)(b * 4 + blockIdx.z) * 512) + j0 + t] = D;
    }
}

// ===========================================================================
// Out = (Fn + softmax @ Fn) * F1.  A = E * scale_j; scale from pm/ps in
// prologue. BM=128 x BN=128.
// ===========================================================================
__global__ __launch_bounds__(256)
void k_mf_af(const u16* __restrict__ E,
             const float* __restrict__ pm, const float* __restrict__ ps,
             const u16* __restrict__ FTh, const u16* __restrict__ FTl,
             const u16* __restrict__ Fh, const u16* __restrict__ Fl,
             const u16* __restrict__ F1h, const u16* __restrict__ F1l,
             u16* __restrict__ Oh, u16* __restrict__ Ol)
{
    __shared__ u16 Ash[BM * LDA_PAD], Asl[BM * LDA_PAD];
    __shared__ u16 Bsh[BN * LDL], Bsl[BN * LDL];
    __shared__ float scl[512];
    const int t = threadIdx.x, lane = t & 63, w = t >> 6;
    const int wr = w >> 1, wc = w & 1;
    const int b = blockIdx.x;
    const int r0 = blockIdx.y * BN, i0 = blockIdx.z * BM;
    const u16* Eb = E + (size_t)b * N_ * N_;
    const size_t tboff = (size_t)b * R_ * N_;
    const int sr = t >> 1, sc = (t & 1) * 16;

    // prologue: scale_j = exp(pm[tile_z,j] - M_j) / D_j
    for (int j = t; j < 512; j += 256) {
        const size_t base = ((size_t)b * 4) * 512 + j;
        float M = pm[base];
        #pragma unroll
        for (int k = 1; k < 4; ++k) M = fmaxf(M, pm[base + (size_t)k * 512]);
        float D = 0.0f;
        #pragma unroll
        for (int k = 0; k < 4; ++k) D += ps[base + (size_t)k * 512] * __expf(pm[base + (size_t)k * 512] - M);
        scl[j] = __expf(pm[base + (size_t)blockIdx.z * 512] - M) / D;
    }
    __syncthreads();

    f32x4 acc[4][4] = {};
    for (int k0 = 0; k0 < N_; k0 += BK) {          // k = j
        const u16* ge = Eb + (size_t)(i0 + sr) * N_ + k0 + sc;
        #pragma unroll
        for (int h = 0; h < 2; ++h) {
            const u16x8 ev = *(const u16x8*)(ge + h * 8);
            u16x8 vh, vl;
            #pragma unroll
            for (int e = 0; e < 8; ++e) {
                const float p = h162f(ev[e]) * scl[k0 + sc + h * 8 + e];
                u16 th, tl;
                split2(p, th, tl);
                vh[e] = th; vl[e] = tl;
            }
            *(u16x8*)&Ash[sr * LDA_PAD + sc + h * 8] = vh;
            *(u16x8*)&Asl[sr * LDA_PAD + sc + h * 8] = vl;
        }
        stage128(FTh + tboff + (size_t)r0 * N_ + k0, N_, Bsh, t);
        stage128(FTl + tboff + (size_t)r0 * N_ + k0, N_, Bsl, t);
        __syncthreads();
        MFMA_TRIPLE_G(acc, Ash, Asl, Bsh, Bsl, LDA_PAD, LDL)
        __syncthreads();
    }
    const int cl2 = lane & 15, rh = lane >> 4;
    #pragma unroll
    for (int m = 0; m < 4; ++m)
        #pragma unroll
        for (int n = 0; n < 4; ++n)
            #pragma unroll
            for (int q = 0; q < 4; ++q) {
                const int row = i0 + wr * 64 + m * 16 + rh * 4 + q;
                const int col = r0 + wc * 64 + n * 16 + cl2;
                const size_t idx = ((size_t)b * N_ + row) * R_ + col;
                const float fn = join2(Fh[idx], Fl[idx]);
                const float f1 = join2(F1h[idx], F1l[idx]);
                split2((fn + acc[m][n][q]) * f1, Oh[idx], Ol[idx]);
            }
}

// WT[n,k] hi/lo = split(W[k,n])
__global__ __launch_bounds__(256)
void k_cvt_wT(const float* __restrict__ Win, u16* __restrict__ WTh,
              u16* __restrict__ WTl, int K, int Nn)
{
    const int idx = blockIdx.x * 256 + threadIdx.x;
    if (idx < K * Nn) {
        const int n = idx / K, k = idx % K;
        split2(Win[(size_t)k * Nn + n], WTh[idx], WTl[idx]);
    }
}

// adj int32 -> 1-bit mask (8 elems -> 1 byte)
__global__ __launch_bounds__(256)
void k_adj_mask(const int* __restrict__ adj, u8* __restrict__ msk, int nbytes)
{
    const int i = blockIdx.x * 256 + threadIdx.x;
    if (i < nbytes) {
        const int4 a  = *(const int4*)(adj + (size_t)i * 8);
        const int4 b2 = *(const int4*)(adj + (size_t)i * 8 + 4);
        u8 m = (u8)((a.x ? 1 : 0) | (a.y ? 2 : 0) | (a.z ? 4 : 0) | (a.w ? 8 : 0) |
                    (b2.x ? 16 : 0) | (b2.y ? 32 : 0) | (b2.z ? 64 : 0) | (b2.w ? 128 : 0));
        msk[i] = m;
    }
}

// ===========================================================================
// Split-K fp32 GEMM + reduce for the thin MLP head (M=64)
// ===========================================================================
#define TS 64
#define FBK 16
__global__ __launch_bounds__(256)
void k_gemm_splitk(const float* __restrict__ A, const float* __restrict__ W,
                   float* __restrict__ Part, int M, int Nn, int K, int klen)
{
    __shared__ float As[FBK][TS];
    __shared__ float Ws[FBK][TS];
    const int tx = threadIdx.x, ty = threadIdx.y;
    const int t  = ty * 16 + tx;
    const int n0 = blockIdx.x * TS;
    const int kb = blockIdx.z * klen;
    const int alm = t >> 2, alk = (t & 3) * 4;
    const int wr  = t >> 4, wc  = (t & 15) * 4;
    float acc[4][4] = {};
    for (int k0 = kb; k0 < kb + klen; k0 += FBK) {
        float4 av = *(const float4*)(A + (size_t)alm * K + k0 + alk);
        As[alk + 0][alm] = av.x; As[alk + 1][alm] = av.y;
        As[alk + 2][alm] = av.z; As[alk + 3][alm] = av.w;
        *(float4*)(&Ws[wr][wc]) = *(const float4*)(W + (size_t)(k0 + wr) * Nn + n0 + wc);
        __syncthreads();
        #pragma unroll
        for (int k = 0; k < FBK; ++k) {
            float a[4], w2[4];
            #pragma unroll
            for (int q = 0; q < 4; ++q) { a[q] = As[k][ty * 4 + q]; w2[q] = Ws[k][tx * 4 + q]; }
            #pragma unroll
            for (int ii = 0; ii < 4; ++ii)
                #pragma unroll
                for (int jj = 0; jj < 4; ++jj)
                    acc[ii][jj] = fmaf(a[ii], w2[jj], acc[ii][jj]);
        }
        __syncthreads();
    }
    float* Pb = Part + (size_t)blockIdx.z * M * Nn;
    #pragma unroll
    for (int ii = 0; ii < 4; ++ii) {
        const int m = ty * 4 + ii;
        #pragma unroll
        for (int jj = 0; jj < 4; ++jj)
            Pb[(size_t)m * Nn + n0 + tx * 4 + jj] = acc[ii][jj];
    }
}

template<int ACT>
__global__ __launch_bounds__(256)
void k_reduce_bias_act(const float* __restrict__ Part, const float* __restrict__ bias,
                       float* __restrict__ C, int MN, int Nn, int SK)
{
    const int i = blockIdx.x * 256 + threadIdx.x;
    if (i < MN) {
        float s = 0.0f;
        for (int k = 0; k < SK; ++k) s += Part[(size_t)k * MN + i];
        float v = s + bias[i % Nn];
        if (ACT) v = silu_f(v);
        C[i] = v;
    }
}

__global__ __launch_bounds__(256)
void k_rownorm(float* __restrict__ f)
{
    __shared__ float red[256];
    const int b = blockIdx.x, t = threadIdx.x;
    float ss = 0.0f;
    for (int c = t; c < HID_; c += 256) {
        const float v = f[(size_t)b * HID_ + c];
        ss += v * v;
    }
    red[t] = ss;
    __syncthreads();
    for (int o = 128; o > 0; o >>= 1) {
        if (t < o) red[t] += red[t + o];
        __syncthreads();
    }
    const float inv = 1.0f / fmaxf(sqrtf(red[0]), 1e-12f);
    for (int c = t; c < HID_; c += 256)
        f[(size_t)b * HID_ + c] *= inv;
}

// ===========================================================================
extern "C" void kernel_launch(void* const* d_in, const int* in_sizes, int n_in,
                              void* d_out, int out_size, void* d_ws, size_t ws_size,
                              hipStream_t stream)
{
    const float* node = (const float*)d_in[0];
    const int*   adj  = (const int*)d_in[1];
    const float* Wv_w = (const float*)d_in[3];  const float* Wv_b = (const float*)d_in[4];
    const float* Ww_w = (const float*)d_in[5];  const float* Ww_b = (const float*)d_in[6];
    const float* Wg_w = (const float*)d_in[7];  const float* Wg_b = (const float*)d_in[8];
    const float* W0 = (const float*)d_in[9];    const float* b0 = (const float*)d_in[10];
    const float* W1 = (const float*)d_in[11];   const float* b1 = (const float*)d_in[12];
    const float* W2 = (const float*)d_in[13];   const float* b2 = (const float*)d_in[14];
    const float* W3 = (const float*)d_in[15];   const float* b3 = (const float*)d_in[16];
    float* out = (float*)d_out;

    float* ws = (float*)d_ws;
    const size_t SZ = (size_t)B_ * N_ * R_;              // 8,388,608 elems
    u16*   E     = (u16*)ws;                             // B*N*N fp16 probs (walk loop)
    float* h0    = ws;                                   // aliases E region (post-loop)
    float* h1    = ws + 98304;
    float* h2    = ws + 196608;
    float* Part  = ws + 262144;                          // 16*98304 floats (post-loop)
    float* f     = ws + (size_t)B_ * N_ * N_;            // 98304
    float* pm    = f + 98304;                            // 131072
    float* ps    = pm + 131072;                          // 131072
    u16* u0   = (u16*)(ps + 131072);
    u16* F1h  = u0;            u16* F1l  = F1h + SZ;
    u16* X1h  = F1l + SZ;      u16* X1l  = X1h + SZ;
    u16* X2h  = X1l + SZ;      u16* X2l  = X2h + SZ;
    u16* XTh  = X2l + SZ;      u16* XTl  = XTh + SZ;
    u16* Ph   = XTl + SZ;      u16* Pl   = Ph + SZ;
    u16* WvTh = Pl + SZ;       u16* WvTl = WvTh + 65536;
    u16* WwTh = WvTl + 65536;  u16* WwTl = WwTh + 65536;
    u16* WgTh = WwTl + 65536;  u16* WgTl = WgTh + 65536;
    u8*  msk  = (u8*)(WgTl + 65536);                     // 2 MB bit-packed

    // --- one-time conversions ---
    k_cvt_wT<<<256, 256, 0, stream>>>(Wv_w, WvTh, WvTl, 256, 256);
    k_cvt_wT<<<256, 256, 0, stream>>>(Ww_w, WwTh, WwTl, 256, 256);
    k_cvt_wT<<<256, 256, 0, stream>>>(Wg_w, WgTh, WgTl, 256, 256);
    k_adj_mask<<<8192, 256, 0, stream>>>(adj, msk, B_ * N_ * N_ / 8);
    (void)hipMemsetAsync(f, 0, 98304 * sizeof(float), stream);

    // --- F1 = silu(node @ Wv + b)  (A = fp32 node, on-the-fly split) ---
    k_mf_gemm<1><<<dim3(2, 256), 256, 0, stream>>>(
        node, WvTh, WvTl, Wv_b, F1h, F1l, B_ * N_, R_, 256);
    // fused: P_1 = F1@Ww + b, f[0] rowsum, F1 -> XT transpose
    k_pwt<1, 1><<<1024, 256, 0, stream>>>(
        F1h, F1l, WwTh, WwTl, WgTh, WgTl, Ww_b, Wg_b, Ph, Pl, XTh, XTl, f, 0);

    const u16 *Xh = F1h, *Xl = F1l;
    u16 *Yh = X1h, *Yl = X1l;
    for (int step = 1; step < L_; ++step) {
        k_mf_abt<<<dim3(64, 4, 4), 256, 0, stream>>>(Ph, Pl, Xh, Xl, msk, E, pm, ps);
        k_mf_af<<<dim3(64, 2, 4), 256, 0, stream>>>(
            E, pm, ps, XTh, XTl, Xh, Xl, F1h, F1l, Yh, Yl);
        if (step < L_ - 1) {
            k_pwt<1, 1><<<1024, 256, 0, stream>>>(
                Yh, Yl, WwTh, WwTl, WgTh, WgTl, Ww_b, Wg_b, Ph, Pl, XTh, XTl, f, step);
        } else {
            k_pwt<0, 0><<<1024, 256, 0, stream>>>(
                Yh, Yl, WwTh, WwTl, WgTh, WgTl, Ww_b, Wg_b, Ph, Pl, XTh, XTl, f, step);
        }
        const u16 *nxh = Yh, *nxl = Yl;
        if (step == 1) { Yh = X2h; Yl = X2l; }
        else           { Yh = (u16*)Xh; Yl = (u16*)Xl; }
        Xh = nxh; Xl = nxl;
    }

    k_rownorm<<<B_, 256, 0, stream>>>(f);

    // --- MLP head (fp32 split-K): 1536 -> 1536 -> 768 -> 128 ---
    const dim3 fblk(16, 16);
    k_gemm_splitk<<<dim3(24, 1, 16), fblk, 0, stream>>>(f,  W0, Part, B_, HID_, HID_, 96);
    k_reduce_bias_act<1><<<384, 256, 0, stream>>>(Part, b0, h0, B_ * HID_, HID_, 16);
    k_gemm_splitk<<<dim3(24, 1, 16), fblk, 0, stream>>>(h0, W1, Part, B_, HID_, HID_, 96);
    k_reduce_bias_act<1><<<384, 256, 0, stream>>>(Part, b1, h1, B_ * HID_, HID_, 16);
    k_gemm_splitk<<<dim3(12, 1, 16), fblk, 0, stream>>>(h1, W2, Part, B_, 768, HID_, 96);
    k_reduce_bias_act<1><<<192, 256, 0, stream>>>(Part, b2, h2, B_ * 768, 768, 16);
    k_gemm_splitk<<<dim3(2, 1, 8),   fblk, 0, stream>>>(h2, W3, Part, B_, 128, 768, 96);
    k_reduce_bias_act<0><<<32, 256, 0, stream>>>(Part, b3, out, B_ * 128, 128, 8);
}

// Round 19
// 742.051 us; speedup vs baseline: 1.1344x; 1.1344x over previous
//
#include <hip/hip_runtime.h>

#define B_   64
#define N_   512
#define R_   256
#define L_   6
#define HID_ 1536

#define BM 128
#define BN 128
#define BK 32
#define LDA_PAD 40   // padded stride for reg-staged A buffers (no bank conflict)
#define LDL 32       // linear stride for global_load_lds buffers

typedef __attribute__((ext_vector_type(4))) float f32x4;
typedef __attribute__((ext_vector_type(8))) __bf16 bf16x8;
typedef __attribute__((ext_vector_type(8))) unsigned short u16x8;
typedef unsigned short u16;
typedef unsigned char  u8;
typedef unsigned int   u32;

__device__ __forceinline__ float silu_f(float x) { return x / (1.0f + __expf(-x)); }

__device__ __forceinline__ float bf2f(u16 h) {
    u32 u = ((u32)h) << 16;
    return __builtin_bit_cast(float, u);
}
// truncation split: x ~= hi + lo with ~17 effective mantissa bits
__device__ __forceinline__ void split2(float x, u16& h, u16& l) {
    u32 u = __builtin_bit_cast(u32, x);
    h = (u16)(u >> 16);
    float r = x - __builtin_bit_cast(float, u & 0xffff0000u);   // exact
    l = (u16)(__builtin_bit_cast(u32, r) >> 16);
}
__device__ __forceinline__ float join2(u16 h, u16 l) {
    return bf2f(h) + bf2f(l);
}
// fp16 storage helpers (probabilities in [0,1])
__device__ __forceinline__ u16 f2h16(float x) {
    _Float16 h = (_Float16)x;
    return __builtin_bit_cast(u16, h);
}
__device__ __forceinline__ float h162f(u16 b) {
    return (float)__builtin_bit_cast(_Float16, b);
}

// ---------------------------------------------------------------------------
// global -> LDS direct (16B/lane). LDS dest is wave-uniform base + lane*16B.
// ---------------------------------------------------------------------------
__device__ __forceinline__ void gll16(const u16* g, u16* l) {
    __builtin_amdgcn_global_load_lds((const __attribute__((address_space(1))) void*)g,
                                     (__attribute__((address_space(3))) void*)l, 16, 0, 0);
}
// 128 rows x 32 cols u16 tile, linear LDS [row*32+col]
__device__ __forceinline__ void stage128(const u16* g, size_t gstride, u16* lds, int t) {
    const int wb = (t >> 6) * 512;
    const int row = t >> 2, col = (t & 3) * 8;
    gll16(g + (size_t)row * gstride + col, lds + wb);
    gll16(g + (size_t)(row + 64) * gstride + col, lds + 2048 + wb);
}
// 64 rows x 32 cols
__device__ __forceinline__ void stage64(const u16* g, size_t gstride, u16* lds, int t) {
    const int wb = (t >> 6) * 512;
    gll16(g + (size_t)(t >> 2) * gstride + (t & 3) * 8, lds + wb);
}

// triple-MFMA on one (ah,al,bh,bl) fragment set
#define TRIPLE1(ACC, AH, AL, BH, BL)                                            \
    ACC = __builtin_amdgcn_mfma_f32_16x16x32_bf16(AH, BH, ACC, 0, 0, 0);        \
    ACC = __builtin_amdgcn_mfma_f32_16x16x32_bf16(AL, BH, ACC, 0, 0, 0);        \
    ACC = __builtin_amdgcn_mfma_f32_16x16x32_bf16(AH, BL, ACC, 0, 0, 0);

// BM=128 x BN=128 core with per-side LDS strides
#define MFMA_TRIPLE_G(ACC, Ash, Asl, Bsh, Bsl, LDA, LDB)                        \
    {                                                                           \
        const int k8 = (lane >> 4) * 8, cl = lane & 15;                         \
        bf16x8 bh[4], bl[4];                                                    \
        _Pragma("unroll")                                                       \
        for (int n = 0; n < 4; ++n) {                                           \
            bh[n] = *(const bf16x8*)&Bsh[(wc * 64 + n * 16 + cl) * LDB + k8];   \
            bl[n] = *(const bf16x8*)&Bsl[(wc * 64 + n * 16 + cl) * LDB + k8];   \
        }                                                                       \
        _Pragma("unroll")                                                       \
        for (int m = 0; m < 4; ++m) {                                           \
            bf16x8 ah = *(const bf16x8*)&Ash[(wr * 64 + m * 16 + cl) * LDA + k8]; \
            bf16x8 al = *(const bf16x8*)&Asl[(wr * 64 + m * 16 + cl) * LDA + k8]; \
            _Pragma("unroll")                                                   \
            for (int n = 0; n < 4; ++n) {                                       \
                TRIPLE1(ACC[m][n], ah, al, bh[n], bl[n])                        \
            }                                                                   \
        }                                                                       \
    }

// ===========================================================================
// C = act(A @ W + bias), A fp32 (on-the-fly split, reg-staged, padded LDS);
// B = WT[Nn,K] hi/lo via global_load_lds (linear LDS).
// ===========================================================================
template<int ACT>
__global__ __launch_bounds__(256)
void k_mf_gemm(const float* __restrict__ Af,
               const u16* __restrict__ WTh, const u16* __restrict__ WTl,
               const float* __restrict__ bias,
               u16* __restrict__ Ch, u16* __restrict__ Cl,
               int M, int Nn, int K)
{
    __shared__ u16 Ash[BM * LDA_PAD], Asl[BM * LDA_PAD];
    __shared__ u16 Bsh[BN * LDL], Bsl[BN * LDL];
    const int t = threadIdx.x, lane = t & 63, w = t >> 6;
    const int wr = w >> 1, wc = w & 1;
    const int m0 = blockIdx.y * BM, n0 = blockIdx.x * BN;
    const int sr = t >> 1, sc = (t & 1) * 16;
    f32x4 acc[4][4] = {};
    for (int k0 = 0; k0 < K; k0 += BK) {
        {
            const float* ga = Af + (size_t)(m0 + sr) * K + k0 + sc;
            u16x8 vh0, vl0, vh1, vl1;
            #pragma unroll
            for (int p = 0; p < 2; ++p) {
                const float4 a = *(const float4*)(ga + p * 8);
                const float4 b = *(const float4*)(ga + p * 8 + 4);
                u16 h, l;
                split2(a.x, h, l); (p ? vh1 : vh0)[0] = h; (p ? vl1 : vl0)[0] = l;
                split2(a.y, h, l); (p ? vh1 : vh0)[1] = h; (p ? vl1 : vl0)[1] = l;
                split2(a.z, h, l); (p ? vh1 : vh0)[2] = h; (p ? vl1 : vl0)[2] = l;
                split2(a.w, h, l); (p ? vh1 : vh0)[3] = h; (p ? vl1 : vl0)[3] = l;
                split2(b.x, h, l); (p ? vh1 : vh0)[4] = h; (p ? vl1 : vl0)[4] = l;
                split2(b.y, h, l); (p ? vh1 : vh0)[5] = h; (p ? vl1 : vl0)[5] = l;
                split2(b.z, h, l); (p ? vh1 : vh0)[6] = h; (p ? vl1 : vl0)[6] = l;
                split2(b.w, h, l); (p ? vh1 : vh0)[7] = h; (p ? vl1 : vl0)[7] = l;
            }
            *(u16x8*)&Ash[sr * LDA_PAD + sc]     = vh0;
            *(u16x8*)&Ash[sr * LDA_PAD + sc + 8] = vh1;
            *(u16x8*)&Asl[sr * LDA_PAD + sc]     = vl0;
            *(u16x8*)&Asl[sr * LDA_PAD + sc + 8] = vl1;
        }
        stage128(WTh + (size_t)n0 * K + k0, K, Bsh, t);
        stage128(WTl + (size_t)n0 * K + k0, K, Bsl, t);
        __syncthreads();
        MFMA_TRIPLE_G(acc, Ash, Asl, Bsh, Bsl, LDA_PAD, LDL)
        __syncthreads();
    }
    const int cl2 = lane & 15, rh = lane >> 4;
    #pragma unroll
    for (int m = 0; m < 4; ++m)
        #pragma unroll
        for (int n = 0; n < 4; ++n) {
            const int col = n0 + wc * 64 + n * 16 + cl2;
            const float bb = bias[col];
            #pragma unroll
            for (int q = 0; q < 4; ++q) {
                const int row = m0 + wr * 64 + m * 16 + rh * 4 + q;
                float v = acc[m][n][q] + bb;
                if (ACT) v = silu_f(v);
                const size_t idx = (size_t)row * Nn + col;
                split2(v, Ch[idx], Cl[idx]);
            }
        }
}

// ===========================================================================
// pw kernel, grid 1024, XCD-swizzled. Single-pass dual-acc at BM2=64.
// DO_T: also emit XT (X transposed) directly from the staged A tiles —
// block n0=0 writes hi plane, n0=1 writes lo plane (balanced, no extra read).
// ===========================================================================
#define BM2 64
template<int DO_P, int DO_T>
__global__ __launch_bounds__(256)
void k_pwt(const u16* __restrict__ Xh, const u16* __restrict__ Xl,
           const u16* __restrict__ WwTh, const u16* __restrict__ WwTl,
           const u16* __restrict__ WgTh, const u16* __restrict__ WgTl,
           const float* __restrict__ bw, const float* __restrict__ bg,
           u16* __restrict__ Ph, u16* __restrict__ Pl,
           u16* __restrict__ XTh, u16* __restrict__ XTl,
           float* __restrict__ f, int step)
{
    __shared__ u16 smem[20480];          // 40 KB
    const int d = blockIdx.x;
    const int t = threadIdx.x;
    const int gid = ((d & 7) << 7) | (d >> 3);             // bijective on [0,1024)
    const int lane = t & 63, w = t >> 6;
    const int m0 = (gid >> 1) * BM2, n0 = (gid & 1) * BN;
    u16* Ash = smem;                     // 64*32
    u16* Asl = smem + 2048;
    u16* Bwh = smem + 4096;              // 128*32 each
    u16* Bwl = smem + 8192;
    u16* Bgh = smem + 12288;
    u16* Bgl = smem + 16384;
    // transposed-write assignment: this block handles one plane
    const u16* Tsrc = (gid & 1) ? Asl : Ash;
    u16*       Tdst = (gid & 1) ? XTl : XTh;
    const int  tb   = m0 >> 9;                 // batch
    const int  ib   = (m0 & 511) + (t & 7) * 8;
    const int  kk   = t >> 3;                  // 0..31
    f32x4 accp[4][2] = {};
    f32x4 accg[4][2] = {};
    for (int k0 = 0; k0 < R_; k0 += BK) {
        stage64(Xh + (size_t)m0 * R_ + k0, R_, Ash, t);
        stage64(Xl + (size_t)m0 * R_ + k0, R_, Asl, t);
        if (DO_P) {
            stage128(WwTh + (size_t)n0 * R_ + k0, R_, Bwh, t);
            stage128(WwTl + (size_t)n0 * R_ + k0, R_, Bwl, t);
        }
        stage128(WgTh + (size_t)n0 * R_ + k0, R_, Bgh, t);
        stage128(WgTl + (size_t)n0 * R_ + k0, R_, Bgl, t);
        __syncthreads();
        {
            const int k8 = (lane >> 4) * 8, cl = lane & 15;
            bf16x8 ah[4], al[4];
            #pragma unroll
            for (int m = 0; m < 4; ++m) {
                ah[m] = *(const bf16x8*)&Ash[(m * 16 + cl) * LDL + k8];
                al[m] = *(const bf16x8*)&Asl[(m * 16 + cl) * LDL + k8];
            }
            #pragma unroll
            for (int n = 0; n < 2; ++n) {
                const int bcol = (w * 32 + n * 16 + cl) * LDL + k8;
                if (DO_P) {
                    bf16x8 bh = *(const bf16x8*)&Bwh[bcol];
                    bf16x8 bl = *(const bf16x8*)&Bwl[bcol];
                    #pragma unroll
                    for (int m = 0; m < 4; ++m) { TRIPLE1(accp[m][n], ah[m], al[m], bh, bl) }
                }
                bf16x8 bh2 = *(const bf16x8*)&Bgh[bcol];
                bf16x8 bl2 = *(const bf16x8*)&Bgl[bcol];
                #pragma unroll
                for (int m = 0; m < 4; ++m) { TRIPLE1(accg[m][n], ah[m], al[m], bh2, bl2) }
            }
        }
        if (DO_T) {
            // write transposed strip XT[tb, k0+kk, ib..ib+8) from staged tile
            u16x8 v;
            #pragma unroll
            for (int e = 0; e < 8; ++e)
                v[e] = Tsrc[((t & 7) * 8 + e) * LDL + kk];
            *(u16x8*)(Tdst + (size_t)tb * R_ * N_ + (size_t)(k0 + kk) * N_ + ib) = v;
        }
        __syncthreads();
    }
    const int cl2 = lane & 15, rh = lane >> 4;
    if (DO_P) {
        #pragma unroll
        for (int m = 0; m < 4; ++m)
            #pragma unroll
            for (int n = 0; n < 2; ++n) {
                const int col = n0 + w * 32 + n * 16 + cl2;
                const float bwv = bw[col];
                #pragma unroll
                for (int q = 0; q < 4; ++q) {
                    const int row = m0 + m * 16 + rh * 4 + q;
                    const size_t idx = (size_t)row * R_ + col;
                    split2(accp[m][n][q] + bwv, Ph[idx], Pl[idx]);
                }
            }
    }
    const int bb = gid >> 4;                     // batch: m0/512
    #pragma unroll
    for (int n = 0; n < 2; ++n) {
        const int col = n0 + w * 32 + n * 16 + cl2;
        const float bias = bg[col];
        float s = 0.0f;
        #pragma unroll
        for (int m = 0; m < 4; ++m)
            #pragma unroll
            for (int q = 0; q < 4; ++q)
                s += silu_f(accg[m][n][q] + bias);
        s += __shfl_xor(s, 16);
        s += __shfl_xor(s, 32);
        if (rh == 0)
            atomicAdd(&f[(size_t)bb * HID_ + step * R_ + col], s);
    }
}

// ===========================================================================
// S-tile = P @ Fn^T masked (u8 mask); writes E = fp16(exp(S - M_tile))
// plus per-tile column stats pm, ps.  (u8 mask: 128-VGPR / 4-wave config)
// ===========================================================================
__global__ __launch_bounds__(256)
void k_mf_abt(const u16* __restrict__ Ph, const u16* __restrict__ Pl,
              const u16* __restrict__ Fh, const u16* __restrict__ Fl,
              const u8* __restrict__ msk, u16* __restrict__ E,
              float* __restrict__ pm, float* __restrict__ ps)
{
    __shared__ u16 Ash[BM * LDL], Asl[BM * LDL];
    __shared__ u16 Bsh[BN * LDL], Bsl[BN * LDL];
    const int t = threadIdx.x, lane = t & 63, w = t >> 6;
    const int wr = w >> 1, wc = w & 1;
    const int b = blockIdx.x;
    const int j0 = blockIdx.y * BN, i0 = blockIdx.z * BM;
    const size_t boff = (size_t)b * N_ * R_;
    f32x4 acc[4][4] = {};
    for (int k0 = 0; k0 < R_; k0 += BK) {
        stage128(Ph + boff + (size_t)i0 * R_ + k0, R_, Ash, t);
        stage128(Pl + boff + (size_t)i0 * R_ + k0, R_, Asl, t);
        stage128(Fh + boff + (size_t)j0 * R_ + k0, R_, Bsh, t);
        stage128(Fl + boff + (size_t)j0 * R_ + k0, R_, Bsl, t);
        __syncthreads();
        MFMA_TRIPLE_G(acc, Ash, Asl, Bsh, Bsl, LDL, LDL)
        __syncthreads();
    }
    const int cl2 = lane & 15, rh = lane >> 4;
    const u8*   mb = msk + (size_t)b * N_ * N_;
    u16*        Eb = E   + (size_t)b * N_ * N_;
    float* smax = (float*)Ash;         // [8][128]
    float* ssum = (float*)Asl;         // [8][128]
    float* Mcol = (float*)Bsh;         // [128]
    const int slot = wr * 4 + rh;
    u32 mbits[4];
    // pass A: mask bits + thread-local column max (masked -> -1e8)
    #pragma unroll
    for (int n = 0; n < 4; ++n) {
        const int col = wc * 64 + n * 16 + cl2;
        u32 mbit = 0;
        float lm = -3.0e38f;
        #pragma unroll
        for (int m = 0; m < 4; ++m)
            #pragma unroll
            for (int q = 0; q < 4; ++q) {
                const int row = i0 + wr * 64 + m * 16 + rh * 4 + q;
                const size_t idx = (size_t)row * N_ + (j0 + col);
                const u32 on = mb[idx] ? 1u : 0u;
                mbit |= on << (m * 4 + q);
                const float v = on ? acc[m][n][q] : -1.0e8f;
                lm = fmaxf(lm, v);
            }
        mbits[n] = mbit;
        smax[slot * 128 + col] = lm;
    }
    __syncthreads();
    if (t < 128) {
        float M = smax[t];
        #pragma unroll
        for (int s2 = 1; s2 < 8; ++s2) M = fmaxf(M, smax[s2 * 128 + t]);
        Mcol[t] = M;
        pm[((size_t)(b * 4 + blockIdx.z) * 512) + j0 + t] = M;
    }
    __syncthreads();
    // pass B: E = fp16(exp(v - M_tile)), accumulate tile column sums
    #pragma unroll
    for (int n = 0; n < 4; ++n) {
        const int col = wc * 64 + n * 16 + cl2;
        const float M = Mcol[col];
        float ls = 0.0f;
        #pragma unroll
        for (int m = 0; m < 4; ++m)
            #pragma unroll
            for (int q = 0; q < 4; ++q) {
                const int row = i0 + wr * 64 + m * 16 + rh * 4 + q;
                const u32 on = (mbits[n] >> (m * 4 + q)) & 1u;
                const float ev = on ? __expf(acc[m][n][q] - M) : 0.0f;
                ls += ev;
                Eb[(size_t)row * N_ + (j0 + col)] = f2h16(ev);
            }
        ssum[slot * 128 + col] = ls;
    }
    __syncthreads();
    if (t < 128) {
        float D = 0.0f;
        #pragma unroll
        for (int s2 = 0; s2 < 8; ++s2) D += ssum[s2 * 128 + t];
        ps[((size_t)(b * 4 + blockIdx.z) * 512) + j0 + t] = D;
    }
}

// ===========================================================================
// Out = (Fn + softmax @ Fn) * F1.  A = E * scale_j; scale from pm/ps in
// prologue. BM=128 x BN=128.
// ===========================================================================
__global__ __launch_bounds__(256)
void k_mf_af(const u16* __restrict__ E,
             const float* __restrict__ pm, const float* __restrict__ ps,
             const u16* __restrict__ FTh, const u16* __restrict__ FTl,
             const u16* __restrict__ Fh, const u16* __restrict__ Fl,
             const u16* __restrict__ F1h, const u16* __restrict__ F1l,
             u16* __restrict__ Oh, u16* __restrict__ Ol)
{
    __shared__ u16 Ash[BM * LDA_PAD], Asl[BM * LDA_PAD];
    __shared__ u16 Bsh[BN * LDL], Bsl[BN * LDL];
    __shared__ float scl[512];
    const int t = threadIdx.x, lane = t & 63, w = t >> 6;
    const int wr = w >> 1, wc = w & 1;
    const int b = blockIdx.x;
    const int r0 = blockIdx.y * BN, i0 = blockIdx.z * BM;
    const u16* Eb = E + (size_t)b * N_ * N_;
    const size_t tboff = (size_t)b * R_ * N_;
    const int sr = t >> 1, sc = (t & 1) * 16;

    // prologue: scale_j = exp(pm[tile_z,j] - M_j) / D_j
    for (int j = t; j < 512; j += 256) {
        const size_t base = ((size_t)b * 4) * 512 + j;
        float M = pm[base];
        #pragma unroll
        for (int k = 1; k < 4; ++k) M = fmaxf(M, pm[base + (size_t)k * 512]);
        float D = 0.0f;
        #pragma unroll
        for (int k = 0; k < 4; ++k) D += ps[base + (size_t)k * 512] * __expf(pm[base + (size_t)k * 512] - M);
        scl[j] = __expf(pm[base + (size_t)blockIdx.z * 512] - M) / D;
    }
    __syncthreads();

    f32x4 acc[4][4] = {};
    for (int k0 = 0; k0 < N_; k0 += BK) {          // k = j
        const u16* ge = Eb + (size_t)(i0 + sr) * N_ + k0 + sc;
        #pragma unroll
        for (int h = 0; h < 2; ++h) {
            const u16x8 ev = *(const u16x8*)(ge + h * 8);
            u16x8 vh, vl;
            #pragma unroll
            for (int e = 0; e < 8; ++e) {
                const float p = h162f(ev[e]) * scl[k0 + sc + h * 8 + e];
                u16 th, tl;
                split2(p, th, tl);
                vh[e] = th; vl[e] = tl;
            }
            *(u16x8*)&Ash[sr * LDA_PAD + sc + h * 8] = vh;
            *(u16x8*)&Asl[sr * LDA_PAD + sc + h * 8] = vl;
        }
        stage128(FTh + tboff + (size_t)r0 * N_ + k0, N_, Bsh, t);
        stage128(FTl + tboff + (size_t)r0 * N_ + k0, N_, Bsl, t);
        __syncthreads();
        MFMA_TRIPLE_G(acc, Ash, Asl, Bsh, Bsl, LDA_PAD, LDL)
        __syncthreads();
    }
    const int cl2 = lane & 15, rh = lane >> 4;
    #pragma unroll
    for (int m = 0; m < 4; ++m)
        #pragma unroll
        for (int n = 0; n < 4; ++n)
            #pragma unroll
            for (int q = 0; q < 4; ++q) {
                const int row = i0 + wr * 64 + m * 16 + rh * 4 + q;
                const int col = r0 + wc * 64 + n * 16 + cl2;
                const size_t idx = ((size_t)b * N_ + row) * R_ + col;
                const float fn = join2(Fh[idx], Fl[idx]);
                const float f1 = join2(F1h[idx], F1l[idx]);
                split2((fn + acc[m][n][q]) * f1, Oh[idx], Ol[idx]);
            }
}

// WT[n,k] hi/lo = split(W[k,n])
__global__ __launch_bounds__(256)
void k_cvt_wT(const float* __restrict__ Win, u16* __restrict__ WTh,
              u16* __restrict__ WTl, int K, int Nn)
{
    const int idx = blockIdx.x * 256 + threadIdx.x;
    if (idx < K * Nn) {
        const int n = idx / K, k = idx % K;
        split2(Win[(size_t)k * Nn + n], WTh[idx], WTl[idx]);
    }
}

// adj int32 -> u8 mask (4 elems/thread)
__global__ __launch_bounds__(256)
void k_adj_mask(const int* __restrict__ adj, u8* __restrict__ msk, int n4)
{
    const int i = blockIdx.x * 256 + threadIdx.x;
    if (i < n4) {
        const int4 a = *(const int4*)(adj + (size_t)i * 4);
        uchar4 m;
        m.x = a.x ? 1 : 0; m.y = a.y ? 1 : 0;
        m.z = a.z ? 1 : 0; m.w = a.w ? 1 : 0;
        *(uchar4*)(msk + (size_t)i * 4) = m;
    }
}

// ===========================================================================
// Split-K fp32 GEMM + reduce for the thin MLP head (M=64)
// ===========================================================================
#define TS 64
#define FBK 16
__global__ __launch_bounds__(256)
void k_gemm_splitk(const float* __restrict__ A, const float* __restrict__ W,
                   float* __restrict__ Part, int M, int Nn, int K, int klen)
{
    __shared__ float As[FBK][TS];
    __shared__ float Ws[FBK][TS];
    const int tx = threadIdx.x, ty = threadIdx.y;
    const int t  = ty * 16 + tx;
    const int n0 = blockIdx.x * TS;
    const int kb = blockIdx.z * klen;
    const int alm = t >> 2, alk = (t & 3) * 4;
    const int wr  = t >> 4, wc  = (t & 15) * 4;
    float acc[4][4] = {};
    for (int k0 = kb; k0 < kb + klen; k0 += FBK) {
        float4 av = *(const float4*)(A + (size_t)alm * K + k0 + alk);
        As[alk + 0][alm] = av.x; As[alk + 1][alm] = av.y;
        As[alk + 2][alm] = av.z; As[alk + 3][alm] = av.w;
        *(float4*)(&Ws[wr][wc]) = *(const float4*)(W + (size_t)(k0 + wr) * Nn + n0 + wc);
        __syncthreads();
        #pragma unroll
        for (int k = 0; k < FBK; ++k) {
            float a[4], w2[4];
            #pragma unroll
            for (int q = 0; q < 4; ++q) { a[q] = As[k][ty * 4 + q]; w2[q] = Ws[k][tx * 4 + q]; }
            #pragma unroll
            for (int ii = 0; ii < 4; ++ii)
                #pragma unroll
                for (int jj = 0; jj < 4; ++jj)
                    acc[ii][jj] = fmaf(a[ii], w2[jj], acc[ii][jj]);
        }
        __syncthreads();
    }
    float* Pb = Part + (size_t)blockIdx.z * M * Nn;
    #pragma unroll
    for (int ii = 0; ii < 4; ++ii) {
        const int m = ty * 4 + ii;
        #pragma unroll
        for (int jj = 0; jj < 4; ++jj)
            Pb[(size_t)m * Nn + n0 + tx * 4 + jj] = acc[ii][jj];
    }
}

template<int ACT>
__global__ __launch_bounds__(256)
void k_reduce_bias_act(const float* __restrict__ Part, const float* __restrict__ bias,
                       float* __restrict__ C, int MN, int Nn, int SK)
{
    const int i = blockIdx.x * 256 + threadIdx.x;
    if (i < MN) {
        float s = 0.0f;
        for (int k = 0; k < SK; ++k) s += Part[(size_t)k * MN + i];
        float v = s + bias[i % Nn];
        if (ACT) v = silu_f(v);
        C[i] = v;
    }
}

__global__ __launch_bounds__(256)
void k_rownorm(float* __restrict__ f)
{
    __shared__ float red[256];
    const int b = blockIdx.x, t = threadIdx.x;
    float ss = 0.0f;
    for (int c = t; c < HID_; c += 256) {
        const float v = f[(size_t)b * HID_ + c];
        ss += v * v;
    }
    red[t] = ss;
    __syncthreads();
    for (int o = 128; o > 0; o >>= 1) {
        if (t < o) red[t] += red[t + o];
        __syncthreads();
    }
    const float inv = 1.0f / fmaxf(sqrtf(red[0]), 1e-12f);
    for (int c = t; c < HID_; c += 256)
        f[(size_t)b * HID_ + c] *= inv;
}

// ===========================================================================
extern "C" void kernel_launch(void* const* d_in, const int* in_sizes, int n_in,
                              void* d_out, int out_size, void* d_ws, size_t ws_size,
                              hipStream_t stream)
{
    const float* node = (const float*)d_in[0];
    const int*   adj  = (const int*)d_in[1];
    const float* Wv_w = (const float*)d_in[3];  const float* Wv_b = (const float*)d_in[4];
    const float* Ww_w = (const float*)d_in[5];  const float* Ww_b = (const float*)d_in[6];
    const float* Wg_w = (const float*)d_in[7];  const float* Wg_b = (const float*)d_in[8];
    const float* W0 = (const float*)d_in[9];    const float* b0 = (const float*)d_in[10];
    const float* W1 = (const float*)d_in[11];   const float* b1 = (const float*)d_in[12];
    const float* W2 = (const float*)d_in[13];   const float* b2 = (const float*)d_in[14];
    const float* W3 = (const float*)d_in[15];   const float* b3 = (const float*)d_in[16];
    float* out = (float*)d_out;

    float* ws = (float*)d_ws;
    const size_t SZ = (size_t)B_ * N_ * R_;              // 8,388,608 elems
    u16*   E     = (u16*)ws;                             // B*N*N fp16 probs (walk loop)
    float* h0    = ws;                                   // aliases E region (post-loop)
    float* h1    = ws + 98304;
    float* h2    = ws + 196608;
    float* Part  = ws + 262144;                          // 16*98304 floats (post-loop)
    float* f     = ws + (size_t)B_ * N_ * N_;            // 98304
    float* pm    = f + 98304;                            // 131072
    float* ps    = pm + 131072;                          // 131072
    u16* u0   = (u16*)(ps + 131072);
    u16* F1h  = u0;            u16* F1l  = F1h + SZ;
    u16* X1h  = F1l + SZ;      u16* X1l  = X1h + SZ;
    u16* X2h  = X1l + SZ;      u16* X2l  = X2h + SZ;
    u16* XTh  = X2l + SZ;      u16* XTl  = XTh + SZ;
    u16* Ph   = XTl + SZ;      u16* Pl   = Ph + SZ;
    u16* WvTh = Pl + SZ;       u16* WvTl = WvTh + 65536;
    u16* WwTh = WvTl + 65536;  u16* WwTl = WwTh + 65536;
    u16* WgTh = WwTl + 65536;  u16* WgTl = WgTh + 65536;
    u8*  msk  = (u8*)(WgTl + 65536);                     // 16.8 MB u8 mask

    // --- one-time conversions ---
    k_cvt_wT<<<256, 256, 0, stream>>>(Wv_w, WvTh, WvTl, 256, 256);
    k_cvt_wT<<<256, 256, 0, stream>>>(Ww_w, WwTh, WwTl, 256, 256);
    k_cvt_wT<<<256, 256, 0, stream>>>(Wg_w, WgTh, WgTl, 256, 256);
    k_adj_mask<<<16384, 256, 0, stream>>>(adj, msk, B_ * N_ * N_ / 4);
    (void)hipMemsetAsync(f, 0, 98304 * sizeof(float), stream);

    // --- F1 = silu(node @ Wv + b)  (A = fp32 node, on-the-fly split) ---
    k_mf_gemm<1><<<dim3(2, 256), 256, 0, stream>>>(
        node, WvTh, WvTl, Wv_b, F1h, F1l, B_ * N_, R_, 256);
    // fused: P_1 = F1@Ww + b, f[0] rowsum, F1 -> XT transpose
    k_pwt<1, 1><<<1024, 256, 0, stream>>>(
        F1h, F1l, WwTh, WwTl, WgTh, WgTl, Ww_b, Wg_b, Ph, Pl, XTh, XTl, f, 0);

    const u16 *Xh = F1h, *Xl = F1l;
    u16 *Yh = X1h, *Yl = X1l;
    for (int step = 1; step < L_; ++step) {
        k_mf_abt<<<dim3(64, 4, 4), 256, 0, stream>>>(Ph, Pl, Xh, Xl, msk, E, pm, ps);
        k_mf_af<<<dim3(64, 2, 4), 256, 0, stream>>>(
            E, pm, ps, XTh, XTl, Xh, Xl, F1h, F1l, Yh, Yl);
        if (step < L_ - 1) {
            k_pwt<1, 1><<<1024, 256, 0, stream>>>(
                Yh, Yl, WwTh, WwTl, WgTh, WgTl, Ww_b, Wg_b, Ph, Pl, XTh, XTl, f, step);
        } else {
            k_pwt<0, 0><<<1024, 256, 0, stream>>>(
                Yh, Yl, WwTh, WwTl, WgTh, WgTl, Ww_b, Wg_b, Ph, Pl, XTh, XTl, f, step);
        }
        const u16 *nxh = Yh, *nxl = Yl;
        if (step == 1) { Yh = X2h; Yl = X2l; }
        else           { Yh = (u16*)Xh; Yl = (u16*)Xl; }
        Xh = nxh; Xl = nxl;
    }

    k_rownorm<<<B_, 256, 0, stream>>>(f);

    // --- MLP head (fp32 split-K): 1536 -> 1536 -> 768 -> 128 ---
    const dim3 fblk(16, 16);
    k_gemm_splitk<<<dim3(24, 1, 16), fblk, 0, stream>>>(f,  W0, Part, B_, HID_, HID_, 96);
    k_reduce_bias_act<1><<<384, 256, 0, stream>>>(Part, b0, h0, B_ * HID_, HID_, 16);
    k_gemm_splitk<<<dim3(24, 1, 16), fblk, 0, stream>>>(h0, W1, Part, B_, HID_, HID_, 96);
    k_reduce_bias_act<1><<<384, 256, 0, stream>>>(Part, b1, h1, B_ * HID_, HID_, 16);
    k_gemm_splitk<<<dim3(12, 1, 16), fblk, 0, stream>>>(h1, W2, Part, B_, 768, HID_, 96);
    k_reduce_bias_act<1><<<192, 256, 0, stream>>>(Part, b2, h2, B_ * 768, 768, 16);
    k_gemm_splitk<<<dim3(2, 1, 8),   fblk, 0, stream>>>(h2, W3, Part, B_, 128, 768, 96);
    k_reduce_bias_act<0><<<32, 256, 0, stream>>>(Part, b3, out, B_ * 128, 128, 8);
}